// Round 5
// baseline (1251.828 us; speedup 1.0000x reference)
//
#include <hip/hip_runtime.h>

#define J 17
#define VO 289            // 17*17
#define NP 320            // padded vo dim (10 x 32 for MFMA K, 20 x 16 for N)
#define LDP 344           // LDS transpose row stride in ushorts (688B: 16B-aligned, bank-spread)
#define NB 8192
#define DIN 2048
#define EPSB 1e-5f

typedef __attribute__((ext_vector_type(8))) short bf16x8;
typedef __attribute__((ext_vector_type(4))) float f32x4;

// adjacency (incl. self) as bitmasks, from SKEL
__device__ __constant__ unsigned ADJM[J] = {
  0x7u, 0xFu, 0x17u, 0x2Au, 0x54u, 0x8E8u, 0x1170u, 0x2A0u, 0x540u,
  0x280u, 0x500u, 0x3820u, 0x5840u, 0xA800u, 0x15000u, 0xA000u, 0x14000u};

__device__ inline unsigned short f2bf(float x){
  unsigned u = __float_as_uint(x);
  return (unsigned short)((u + 0x7fffu + ((u>>16)&1u)) >> 16);   // RNE
}

__global__ void zero_stats(float* p, int n) {
  int i = blockIdx.x*blockDim.x + threadIdx.x;
  int stride = gridDim.x*blockDim.x;
  for (; i < n; i += stride) p[i] = 0.f;
}

// -------- prepass: W0 [17][2048][17] f32 -> Wbt [17][32 cols][2048 k] bf16
__global__ __launch_bounds__(256) void wconv_kernel(
    const float* __restrict__ W0, unsigned short* __restrict__ Wbt)
{
  int t = blockIdx.x*256 + threadIdx.x;    // t = v*2048 + k
  int v = t >> 11, k = t & 2047;
  const float* src = W0 + (size_t)t*J;
  unsigned short* dst = Wbt + ((size_t)v*32 << 11) + k;
  #pragma unroll
  for (int o=0;o<J;++o)  dst[(size_t)o<<11] = f2bf(src[o]);
  #pragma unroll
  for (int o=J;o<32;++o) dst[(size_t)o<<11] = 0;
}

// -------- prepass: static block-diag conv matrices B2_s[n=(v,o)][k=(u,d)] = (u==v)?Wr[s][v][d][o]:0
__global__ __launch_bounds__(256) void b2_kernel(
    const float* __restrict__ Wr, unsigned short* __restrict__ B2a)
{
  int t = blockIdx.x*256 + threadIdx.x;
  if (t >= 8*NP) return;
  int s = t/NP, n = t - s*NP;
  unsigned short* row = B2a + ((size_t)s*NP + n)*NP;
  for (int k=0;k<NP;++k) row[k] = 0;
  if (n < VO) {
    int v = n/J, o = n - v*J;
    const float* w = Wr + (size_t)(s*J + v)*J*J + o;   // Wr[s][v][d][o], d stride J
    #pragma unroll
    for (int d=0; d<J; ++d) row[v*J + d] = f2bf(w[(size_t)d*J]);
  }
}

// -------- per-stage builder: B1[n=(v,o)][k=(u,oo)] = (oo==o && Adj[v,u]) * (g/sigma)[u,o];
//          c1[n] = sum_u Adj[v,u] * (be - mu*g/sigma)[u,o]
__global__ __launch_bounds__(320) void b1_kernel(
    const float* __restrict__ statJ, const float* __restrict__ g,
    const float* __restrict__ be, unsigned short* __restrict__ B1,
    float* __restrict__ c1)
{
  __shared__ float As[VO], Cs[VO];
  const int t = threadIdx.x;
  if (t < VO) {
    float s=0.f, q=0.f;
    #pragma unroll
    for (int r=0;r<8;++r){ s += statJ[r*512+t]; q += statJ[4096+r*512+t]; }
    float mu  = s*(1.f/NB);
    float var = q*(1.f/NB) - mu*mu;
    float A = g[t]*rsqrtf(var + EPSB);
    As[t]=A; Cs[t]=be[t]-mu*A;
  }
  __syncthreads();
  if (blockIdx.x == 0 && t < NP) {
    float c = 0.f;
    if (t < VO) {
      int v=t/J, o=t-v*J; unsigned m=ADJM[v];
      for (int u=0;u<J;++u) if ((m>>u)&1u) c += Cs[u*J+o];
    }
    c1[t] = c;
  }
  const int n = blockIdx.x*40 + (t>>3);
  const int ks = (t&7)*40;
  unsigned short* row = B1 + (size_t)n*NP + ks;
  if (n < VO) {
    const int v=n/J, o=n-v*J; const unsigned m=ADJM[v];
    for (int k=ks;k<ks+40;++k){
      unsigned short val = 0;
      if (k < VO) { int u=k/J, oo=k-u*J; if (oo==o && ((m>>u)&1u)) val = f2bf(As[u*J+o]); }
      row[k-ks] = val;
    }
  } else {
    for (int k=0;k<40;++k) row[k]=0;
  }
}

// -------- conv0: per-vertex GEMM [8192,2048]x[2048,17->32] via bf16 MFMA; writes X0 bf16 + BN stats
__global__ __launch_bounds__(256) void conv0_kernel(
    const float* __restrict__ feat, const unsigned short* __restrict__ Wbt,
    const float* __restrict__ b0, unsigned short* __restrict__ X0,
    float* __restrict__ stat0)
{
  const int v = blockIdx.y;
  const int tid = threadIdx.x, w = tid>>6, l = tid&63;
  const int lo = l&15, oc = l>>4;
  const int rowBlk = blockIdx.x*128;

  __shared__ __align__(16) unsigned short Abuf[2][128*64];
  __shared__ float bstat[34];
  if (tid < 34) bstat[tid] = 0.f;

  f32x4 acc[2][2];
  #pragma unroll
  for (int m=0;m<2;++m)
    #pragma unroll
    for (int n=0;n<2;++n)
      acc[m][n] = (f32x4){0.f,0.f,0.f,0.f};

  const unsigned short* Wv = Wbt + ((size_t)v*32 << 11);

  auto stage = [&](int buf, int kc) {
    const int kq = lo*4;
    #pragma unroll
    for (int i=0;i<8;++i) {
      const int r = w*32 + i*4 + oc;
      const float4 fv = *(const float4*)(feat + ((size_t)(rowBlk + r)*J + v)*DIN + kc*64 + kq);
      ushort4 hv;
      hv.x = f2bf(fv.x); hv.y = f2bf(fv.y); hv.z = f2bf(fv.z); hv.w = f2bf(fv.w);
      const int idx = (r*64 + kq) ^ ((r&7)<<3);
      *(ushort4*)&Abuf[buf][idx] = hv;
    }
  };

  stage(0, 0);
  __syncthreads();

  const int r0 = w*32 + lo, r1 = w*32 + 16 + lo;
  const int sw0 = (r0&7)<<3, sw1 = (r1&7)<<3;

  for (int kc=0; kc<DIN/64; ++kc) {
    const int buf = kc & 1;
    if (kc < DIN/64 - 1) stage(buf^1, kc+1);
    #pragma unroll
    for (int ks=0; ks<2; ++ks) {
      const int kb = ks*32 + oc*8;
      bf16x8 a0 = *(const bf16x8*)&Abuf[buf][(r0*64 + kb) ^ sw0];
      bf16x8 a1 = *(const bf16x8*)&Abuf[buf][(r1*64 + kb) ^ sw1];
      const size_t kg = (size_t)kc*64 + kb;
      bf16x8 b0f = *(const bf16x8*)(Wv + ((size_t)lo      << 11) + kg);
      bf16x8 b1f = *(const bf16x8*)(Wv + ((size_t)(16+lo) << 11) + kg);
      acc[0][0] = __builtin_amdgcn_mfma_f32_16x16x32_bf16(a0, b0f, acc[0][0], 0,0,0);
      acc[0][1] = __builtin_amdgcn_mfma_f32_16x16x32_bf16(a0, b1f, acc[0][1], 0,0,0);
      acc[1][0] = __builtin_amdgcn_mfma_f32_16x16x32_bf16(a1, b0f, acc[1][0], 0,0,0);
      acc[1][1] = __builtin_amdgcn_mfma_f32_16x16x32_bf16(a1, b1f, acc[1][1], 0,0,0);
    }
    __syncthreads();
  }

  const float bias0 = b0[v*J + lo];
  const float bias1 = (lo==0) ? b0[v*J + 16] : 0.f;
  float s0=0.f,q0=0.f,s1=0.f,q1=0.f;
  #pragma unroll
  for (int m=0;m<2;++m) {
    #pragma unroll
    for (int r=0;r<4;++r) {
      const int row = rowBlk + w*32 + m*16 + oc*4 + r;
      const float h0 = acc[m][0][r] + bias0;
      X0[(size_t)row*NP + v*J + lo] = f2bf(h0);
      s0 += h0; q0 += h0*h0;
      if (lo==0) {
        const float h1 = acc[m][1][r] + bias1;
        X0[(size_t)row*NP + v*J + 16] = f2bf(h1);
        s1 += h1; q1 += h1*h1;
      }
    }
  }
  s0 += __shfl_xor(s0,16); s0 += __shfl_xor(s0,32);
  q0 += __shfl_xor(q0,16); q0 += __shfl_xor(q0,32);
  s1 += __shfl_xor(s1,16); s1 += __shfl_xor(s1,32);
  q1 += __shfl_xor(q1,16); q1 += __shfl_xor(q1,32);
  if (l < 16) { atomicAdd(&bstat[lo], s0); atomicAdd(&bstat[17+lo], q0); }
  if (l == 0) { atomicAdd(&bstat[16], s1); atomicAdd(&bstat[33], q1); }
  __syncthreads();
  const int rep = blockIdx.x & 7;
  if (tid < 17)       atomicAdd(&stat0[rep*512 + v*J + tid], bstat[tid]);
  else if (tid < 34)  atomicAdd(&stat0[4096 + rep*512 + v*J + (tid-17)], bstat[tid]);
}

// -------- chain stage as 2 MFMA GEMMs: X(bf16)·B1 -> +c1,relu,[resid],[F] -> ldsT -> ·B2 -> +bias,stats -> Xnext
// grid 256 blocks, block 128 (2 waves), each wave owns 16 rows; N = K = 320.
template<int RESID,int WRITEF,int FINAL>
__global__ __launch_bounds__(128) void cg_kernel(
  const unsigned short* __restrict__ Xin, unsigned short* __restrict__ Xout,
  float* __restrict__ F, float* __restrict__ outF,
  const float* __restrict__ c1, const unsigned short* __restrict__ B1,
  const unsigned short* __restrict__ B2, const float* __restrict__ br_s,
  float* __restrict__ statN)
{
  __shared__ unsigned short ldsa[2][16][LDP];
  __shared__ float c1s[NP], b2b[NP];
  __shared__ float sst[NP], ssq[NP];
  const int tid = threadIdx.x, wv = tid>>6, l = tid&63;
  const int lo = l&15, oc = l>>4;
  const int rowBase = blockIdx.x*32 + wv*16;

  for (int i=tid;i<NP;i+=128){
    c1s[i] = c1[i];
    if (!FINAL){ b2b[i] = (i<VO) ? br_s[i] : 0.f; sst[i]=0.f; ssq[i]=0.f; }
  }
  __syncthreads();

  // ---- GEMM1: a = X · B1
  f32x4 acc[20];
  #pragma unroll
  for (int nf=0;nf<20;++nf) acc[nf] = (f32x4){0.f,0.f,0.f,0.f};
  const unsigned short* arow  = Xin + (size_t)(rowBase+lo)*NP + oc*8;
  const unsigned short* bbase = B1  + (size_t)lo*NP + oc*8;
  for (int kc=0;kc<10;++kc){
    bf16x8 a = *(const bf16x8*)(arow + kc*32);
    #pragma unroll
    for (int nf=0;nf<20;++nf){
      bf16x8 b = *(const bf16x8*)(bbase + (size_t)(nf*16)*NP + kc*32);
      acc[nf] = __builtin_amdgcn_mfma_f32_16x16x32_bf16(a, b, acc[nf], 0,0,0);
    }
  }

  // ---- epilogue 1: +c1, relu, resid/F, transpose to LDS (or final store)
  #pragma unroll
  for (int nf=0;nf<20;++nf){
    const int col = nf*16 + lo;
    #pragma unroll
    for (int r=0;r<4;++r){
      const int row = rowBase + oc*4 + r;
      float x = acc[nf][r] + c1s[col];
      x = x>0.f ? x : 0.f;
      if (col < VO){
        const size_t gi = (size_t)row*VO + col;
        if (RESID)  x += F[gi];
        if (WRITEF) F[gi] = x;
        if (FINAL)  outF[gi] = x;
      }
      if (!FINAL) ldsa[wv][oc*4+r][col] = f2bf(x);
    }
  }
  if (FINAL) return;
  asm volatile("s_waitcnt lgkmcnt(0)" ::: "memory");

  // ---- GEMM2: y = a · B2  (a re-read from per-wave LDS rows, k-contiguous)
  f32x4 acc2[20];
  #pragma unroll
  for (int nf=0;nf<20;++nf) acc2[nf] = (f32x4){0.f,0.f,0.f,0.f};
  const unsigned short* a2row  = &ldsa[wv][lo][oc*8];
  const unsigned short* b2base = B2 + (size_t)lo*NP + oc*8;
  for (int kc=0;kc<10;++kc){
    bf16x8 a = *(const bf16x8*)(a2row + kc*32);
    #pragma unroll
    for (int nf=0;nf<20;++nf){
      bf16x8 b = *(const bf16x8*)(b2base + (size_t)(nf*16)*NP + kc*32);
      acc2[nf] = __builtin_amdgcn_mfma_f32_16x16x32_bf16(a, b, acc2[nf], 0,0,0);
    }
  }

  // ---- epilogue 2: +bias, Xout bf16, BN stats
  #pragma unroll
  for (int nf=0;nf<20;++nf){
    const int col = nf*16 + lo;
    float s=0.f, q=0.f;
    #pragma unroll
    for (int r=0;r<4;++r){
      const int row = rowBase + oc*4 + r;
      const float y = acc2[nf][r] + b2b[col];
      Xout[(size_t)row*NP + col] = f2bf(y);
      s += y; q += y*y;
    }
    s += __shfl_xor(s,16); s += __shfl_xor(s,32);
    q += __shfl_xor(q,16); q += __shfl_xor(q,32);
    if (l < 16 && col < VO){ atomicAdd(&sst[col], s); atomicAdd(&ssq[col], q); }
  }
  __syncthreads();
  const int rep = blockIdx.x & 7;
  for (int i=tid;i<VO;i+=128){
    atomicAdd(&statN[rep*512+i],        sst[i]);
    atomicAdd(&statN[4096 + rep*512+i], ssq[i]);
  }
}

extern "C" void kernel_launch(void* const* d_in, const int* in_sizes, int n_in,
                              void* d_out, int out_size, void* d_ws, size_t ws_size,
                              hipStream_t stream)
{
  (void)in_sizes; (void)n_in; (void)out_size; (void)ws_size;
  const float* img = (const float*)d_in[0];
  const float* W0  = (const float*)d_in[1];
  const float* b0  = (const float*)d_in[2];
  const float* g0  = (const float*)d_in[3];
  const float* be0 = (const float*)d_in[4];
  const float* Wr  = (const float*)d_in[5];
  const float* br  = (const float*)d_in[6];
  const float* gr  = (const float*)d_in[7];
  const float* ber = (const float*)d_in[8];

  float* ws = (float*)d_ws;
  float* ST = ws;                                              // 9*8192 f32
  unsigned short* Wbt = (unsigned short*)(ws + 73728);         // 17*32*2048 ush
  unsigned short* B2a = (unsigned short*)(ws + 73728 + 557056);            // 8*320*320 ush
  unsigned short* B1  = (unsigned short*)(ws + 73728 + 557056 + 409600);   // 320*320 ush
  float* c1 = ws + 73728 + 557056 + 409600 + 51200;            // 320 f32
  float* F  = c1 + 320;                                        // 8192*289 f32
  unsigned short* Xa = (unsigned short*)(F + (size_t)NB*VO);   // 8192*320 ush
  unsigned short* Xb = (unsigned short*)((float*)Xa + (size_t)NB*NP/2);
  float* out = (float*)d_out;

  zero_stats<<<72,256,0,stream>>>(ST, 9*8192);
  wconv_kernel<<<136,256,0,stream>>>(W0, Wbt);
  b2_kernel<<<10,256,0,stream>>>(Wr, B2a);

  conv0_kernel<<<dim3(64,17),256,0,stream>>>(img, Wbt, b0, Xa, ST);

  #define STG(j) (ST + (size_t)(j)*8192)
  #define B2S(s) (B2a + (size_t)(s)*NP*NP)

  // stage 0: BN0 -> adj -> relu -> writeF ; conv Wr0 -> stats1
  b1_kernel<<<8,320,0,stream>>>(STG(0), g0, be0, B1, c1);
  cg_kernel<0,1,0><<<256,128,0,stream>>>(Xa, Xb, F, nullptr, c1, B1, B2S(0), br+0*VO, STG(1));
  // stage 1
  b1_kernel<<<8,320,0,stream>>>(STG(1), gr+0*VO, ber+0*VO, B1, c1);
  cg_kernel<0,0,0><<<256,128,0,stream>>>(Xb, Xa, F, nullptr, c1, B1, B2S(1), br+1*VO, STG(2));
  // stage 2: resid + writeF
  b1_kernel<<<8,320,0,stream>>>(STG(2), gr+1*VO, ber+1*VO, B1, c1);
  cg_kernel<1,1,0><<<256,128,0,stream>>>(Xa, Xb, F, nullptr, c1, B1, B2S(2), br+2*VO, STG(3));
  // stage 3
  b1_kernel<<<8,320,0,stream>>>(STG(3), gr+2*VO, ber+2*VO, B1, c1);
  cg_kernel<0,0,0><<<256,128,0,stream>>>(Xb, Xa, F, nullptr, c1, B1, B2S(3), br+3*VO, STG(4));
  // stage 4: resid + writeF
  b1_kernel<<<8,320,0,stream>>>(STG(4), gr+3*VO, ber+3*VO, B1, c1);
  cg_kernel<1,1,0><<<256,128,0,stream>>>(Xa, Xb, F, nullptr, c1, B1, B2S(4), br+4*VO, STG(5));
  // stage 5
  b1_kernel<<<8,320,0,stream>>>(STG(5), gr+4*VO, ber+4*VO, B1, c1);
  cg_kernel<0,0,0><<<256,128,0,stream>>>(Xb, Xa, F, nullptr, c1, B1, B2S(5), br+5*VO, STG(6));
  // stage 6: resid + writeF
  b1_kernel<<<8,320,0,stream>>>(STG(6), gr+5*VO, ber+5*VO, B1, c1);
  cg_kernel<1,1,0><<<256,128,0,stream>>>(Xa, Xb, F, nullptr, c1, B1, B2S(6), br+6*VO, STG(7));
  // stage 7
  b1_kernel<<<8,320,0,stream>>>(STG(7), gr+6*VO, ber+6*VO, B1, c1);
  cg_kernel<0,0,0><<<256,128,0,stream>>>(Xb, Xa, F, nullptr, c1, B1, B2S(7), br+7*VO, STG(8));
  // stage 8 (final): BN8 -> adj -> relu -> +F -> d_out
  b1_kernel<<<8,320,0,stream>>>(STG(8), gr+7*VO, ber+7*VO, B1, c1);
  cg_kernel<1,0,1><<<256,128,0,stream>>>(Xa, nullptr, F, out, c1, B1, nullptr, nullptr, nullptr);

  #undef STG
  #undef B2S
}

// Round 6
// 503.124 us; speedup vs baseline: 2.4881x; 2.4881x over previous
//
#include <hip/hip_runtime.h>

#define J 17
#define JP 18             // padded inner dim (2-way LDS bank alias = free)
#define VO 289            // 17*17
#define NB 8192
#define DIN 2048
#define EPSB 1e-5f
#define KC 512            // conv0: k-floats per staged chunk (2KB per row)
#define RT 16             // conv0: rows per block
#define NCH 68            // 17*2048/512 chunks per row

typedef __attribute__((ext_vector_type(8))) short bf16x8;
typedef __attribute__((ext_vector_type(4))) float f32x4;

// adjacency (incl. self) as bitmasks, from SKEL
__device__ __constant__ unsigned ADJM[J] = {
  0x7u, 0xFu, 0x17u, 0x2Au, 0x54u, 0x8E8u, 0x1170u, 0x2A0u, 0x540u,
  0x280u, 0x500u, 0x3820u, 0x5840u, 0xA800u, 0x15000u, 0xA000u, 0x14000u};

__device__ inline unsigned short f2bf(float x){
  unsigned u = __float_as_uint(x);
  return (unsigned short)((u + 0x7fffu + ((u>>16)&1u)) >> 16);   // RNE
}

__global__ void zero_stats(float* p, int n) {
  int i = blockIdx.x*blockDim.x + threadIdx.x;
  int stride = gridDim.x*blockDim.x;
  for (; i < n; i += stride) p[i] = 0.f;
}

// -------- prepass: W0 [17][2048][17] f32 -> Wbt [17][32 cols][2048 k] bf16 (cols 17..31 zero)
__global__ __launch_bounds__(256) void wconv_kernel(
    const float* __restrict__ W0, unsigned short* __restrict__ Wbt)
{
  int t = blockIdx.x*256 + threadIdx.x;    // t = v*2048 + k
  int v = t >> 11, k = t & 2047;
  const float* src = W0 + (size_t)t*J;
  unsigned short* dst = Wbt + ((size_t)v*32 << 11) + k;
  #pragma unroll
  for (int o=0;o<J;++o)  dst[(size_t)o<<11] = f2bf(src[o]);
  #pragma unroll
  for (int o=J;o<32;++o) dst[(size_t)o<<11] = 0;
}

// -------- conv0 v2: streaming per-row GEMM. 512 blocks x 16 rows, block 256 (4 waves).
// Each row consumed LINEARLY (v-major): chunk c covers floats [c*512, c*512+512) of the
// row's 34816; v = c>>2. Loads issued early to regs, MFMA on previous chunk, write-late.
// Waves k-split the 512-chunk (128 k each); cross-wave reduce at each v boundary.
__global__ __launch_bounds__(256) void conv0_kernel(
    const float* __restrict__ feat, const unsigned short* __restrict__ Wbt,
    const float* __restrict__ b0, float* __restrict__ C,
    float* __restrict__ stat0)
{
  const int tid = threadIdx.x, w = tid>>6, l = tid&63;
  const int lo = l&15, oc = l>>4;
  const int sr = tid>>4, sc = tid&15;       // staging: row, col-group
  const int rowBase = blockIdx.x*RT;

  __shared__ __align__(16) unsigned short Ab[2][RT*KC];   // 32 KB, XOR-swizzled
  __shared__ float red[4][2][256];                        // 8 KB cross-wave reduce
  __shared__ float bS[VO], bQ[VO];                        // block-local BN stats

  for (int i=tid;i<VO;i+=256){ bS[i]=0.f; bQ[i]=0.f; }

  f32x4 acc0 = (f32x4){0.f,0.f,0.f,0.f};
  f32x4 acc1 = (f32x4){0.f,0.f,0.f,0.f};

  const float* frow = feat + (size_t)(rowBase + sr)*(J*DIN);
  float4 ld[8];

  auto issue = [&](int c){
    const float* src = frow + c*KC + sc*4;
    #pragma unroll
    for (int i=0;i<8;++i) ld[i] = *(const float4*)(src + i*64);
  };
  auto writeLDS = [&](int buf){
    #pragma unroll
    for (int i=0;i<8;++i){
      ushort4 hv;
      hv.x=f2bf(ld[i].x); hv.y=f2bf(ld[i].y); hv.z=f2bf(ld[i].z); hv.w=f2bf(ld[i].w);
      const int f = sc*4 + i*64;
      *(ushort4*)&Ab[buf][(sr*KC + f) ^ ((sr&7)<<3)] = hv;
    }
  };

  issue(0); writeLDS(0);
  __syncthreads();

  const int swz = (lo&7)<<3;

  for (int c=0;c<NCH;++c){
    const int buf = c&1;
    if (c+1<NCH) issue(c+1);
    const int v = c>>2;
    const unsigned short* Wv = Wbt + ((size_t)v*32 << 11);
    #pragma unroll
    for (int ks=0;ks<4;++ks){
      const int kl = w*128 + ks*32 + oc*8;       // k within chunk
      bf16x8 a = *(const bf16x8*)&Ab[buf][(lo*KC + kl) ^ swz];
      const int kg = (c&3)*KC + kl;              // k within v
      bf16x8 bA = *(const bf16x8*)(Wv + ((size_t)lo<<11) + kg);
      bf16x8 bB = *(const bf16x8*)(Wv + ((size_t)(16+lo)<<11) + kg);
      acc0 = __builtin_amdgcn_mfma_f32_16x16x32_bf16(a, bA, acc0, 0,0,0);
      acc1 = __builtin_amdgcn_mfma_f32_16x16x32_bf16(a, bB, acc1, 0,0,0);
    }
    if ((c&3)==3){
      // v complete: cross-wave k-split reduce + epilogue
      #pragma unroll
      for (int r=0;r<4;++r){
        red[w][0][(oc*4+r)*16+lo] = acc0[r];
        red[w][1][(oc*4+r)*16+lo] = acc1[r];
      }
      acc0 = (f32x4){0.f,0.f,0.f,0.f};
      acc1 = (f32x4){0.f,0.f,0.f,0.f};
      __syncthreads();
      // thread t = (sr,sc): output row sr, col sc (and col 16 for sc==0)
      const int ri = sr*16+sc;
      float h0 = red[0][0][ri]+red[1][0][ri]+red[2][0][ri]+red[3][0][ri] + b0[v*J+sc];
      C[(size_t)(rowBase+sr)*VO + v*J + sc] = h0;
      float s0 = h0, q0 = h0*h0;
      float s1 = 0.f, q1 = 0.f;
      if (sc==0){
        const int r2 = sr*16;
        float h1 = red[0][1][r2]+red[1][1][r2]+red[2][1][r2]+red[3][1][r2] + b0[v*J+16];
        C[(size_t)(rowBase+sr)*VO + v*J + 16] = h1;
        s1 = h1; q1 = h1*h1;
      }
      s0 += __shfl_xor(s0,16); s0 += __shfl_xor(s0,32);
      q0 += __shfl_xor(q0,16); q0 += __shfl_xor(q0,32);
      s1 += __shfl_xor(s1,16); s1 += __shfl_xor(s1,32);
      q1 += __shfl_xor(q1,16); q1 += __shfl_xor(q1,32);
      if (l < 16){ atomicAdd(&bS[v*J+l], s0); atomicAdd(&bQ[v*J+l], q0); }
      if (l == 0){ atomicAdd(&bS[v*J+16], s1); atomicAdd(&bQ[v*J+16], q1); }
    }
    if (c+1<NCH){
      writeLDS(buf^1);
      __syncthreads();
    }
  }

  __syncthreads();
  const int rep = blockIdx.x & 7;
  for (int i=tid;i<VO;i+=256){
    atomicAdd(&stat0[rep*512+i],        bS[i]);
    atomicAdd(&stat0[4096 + rep*512+i], bQ[i]);
  }
}

// -------- chain: BN_j (8-replica stats) -> bitmask adjacency -> ReLU [-> resid/F]
//          [-> conv_{j+1} (transposed W, 2-row pairing) -> replica stats]
// grid 512 x 16 rows, block 256 (4 waves; each wave 2 pairs of 2 rows)  [round-4 verbatim]
template<int RESID,int WRITEF,int CONV>
__global__ __launch_bounds__(256) void chain_kernel(
  const float* __restrict__ Cin, float* __restrict__ Cout,
  float* __restrict__ F,
  const float* __restrict__ statJ,
  const float* __restrict__ g, const float* __restrict__ be,
  const float* __restrict__ Wc, const float* __restrict__ bc,
  float* __restrict__ statN)
{
  __shared__ float wsmT[J*J*JP];      // [v][o][d], d-contiguous
  __shared__ float bb[VO];
  __shared__ float aC[VO], cC[VO];
  __shared__ float hbX[4][2][J*JP];   // per-wave, 2 rows, [vertex][chan] padded
  __shared__ float ssum[VO], ssq[VO];
  const int tid = threadIdx.x, wv = tid>>6, lane = tid&63;

  if (CONV) {
    for (int i=tid;i<J*J*J;i+=256) {
      int v = i/VO, rem = i - v*VO, d = rem/J, o = rem - d*J;
      wsmT[(v*J+o)*JP + d] = Wc[i];
    }
    for (int i=tid;i<VO;i+=256) bb[i]=bc[i];
  }
  for (int i=tid;i<VO;i+=256) {
    float s=0.f,q=0.f;
    #pragma unroll
    for (int r=0;r<8;++r){ s += statJ[r*512+i]; q += statJ[4096 + r*512+i]; }
    float mu  = s*(1.f/NB);
    float var = q*(1.f/NB) - mu*mu;
    float rs  = rsqrtf(var + EPSB);
    float A = rs*g[i];
    aC[i]=A; cC[i]=be[i]-mu*A;
    ssum[i]=0.f; ssq[i]=0.f;
  }
  __syncthreads();

  float sl[5]={0,0,0,0,0}, ql[5]={0,0,0,0,0};

  #pragma unroll
  for (int it=0; it<2; ++it) {
    const int r0 = blockIdx.x*16 + wv*4 + it*2;   // rows r0, r0+1
    const float* c0 = Cin + (size_t)r0*VO;
    const float* c1 = c0 + VO;

    #pragma unroll
    for (int s=0;s<5;++s) {
      int vo = lane + 64*s;
      if (vo<VO) {
        int vtx = vo/J, o = vo - vtx*J;
        hbX[wv][0][vtx*JP+o] = c0[vo]*aC[vo] + cC[vo];
        hbX[wv][1][vtx*JP+o] = c1[vo]*aC[vo] + cC[vo];
      }
    }
    asm volatile("s_waitcnt lgkmcnt(0)" ::: "memory");

    float n0[5], n1[5];
    #pragma unroll
    for (int s=0;s<5;++s) {
      int vo = lane + 64*s;
      n0[s]=0.f; n1[s]=0.f;
      if (vo<VO) {
        int vtx = vo/J, o = vo - vtx*J;
        unsigned m = ADJM[vtx];
        float a0=0.f, a1=0.f;
        while (m) {
          int u = __ffs(m) - 1; m &= m-1;
          a0 += hbX[wv][0][u*JP+o];
          a1 += hbX[wv][1][u*JP+o];
        }
        a0 = a0>0.f?a0:0.f; a1 = a1>0.f?a1:0.f;
        size_t gi = (size_t)r0*VO + vo;
        if (RESID)  { a0 += F[gi]; a1 += F[gi+VO]; }
        if (WRITEF) { F[gi]=a0;    F[gi+VO]=a1; }
        n0[s]=a0; n1[s]=a1;
        if (!CONV) { Cout[gi]=a0; Cout[gi+VO]=a1; }
      }
    }

    if (CONV) {
      #pragma unroll
      for (int s=0;s<5;++s) {
        int vo = lane + 64*s;
        if (vo<VO) {
          int vtx = vo/J, o = vo - vtx*J;
          hbX[wv][0][vtx*JP+o] = n0[s];
          hbX[wv][1][vtx*JP+o] = n1[s];
        }
      }
      asm volatile("s_waitcnt lgkmcnt(0)" ::: "memory");
      #pragma unroll
      for (int s=0;s<5;++s) {
        int vo = lane + 64*s;
        if (vo<VO) {
          int vtx = vo/J, o = vo - vtx*J;
          const float* wp = &wsmT[(vtx*J+o)*JP];
          const float* h0 = &hbX[wv][0][vtx*JP];
          const float* h1 = &hbX[wv][1][vtx*JP];
          float a0 = bb[vo], a1 = a0;
          #pragma unroll
          for (int d=0;d<J;++d) {
            float w = wp[d];
            a0 += h0[d]*w; a1 += h1[d]*w;
          }
          size_t gi = (size_t)r0*VO + vo;
          Cout[gi]=a0; Cout[gi+VO]=a1;
          sl[s] += a0+a1; ql[s] += a0*a0 + a1*a1;
        }
      }
      asm volatile("s_waitcnt lgkmcnt(0)" ::: "memory");
    } else {
      asm volatile("s_waitcnt lgkmcnt(0)" ::: "memory");
    }
  }

  if (CONV) {
    #pragma unroll
    for (int s=0;s<5;++s) {
      int vo = lane + 64*s;
      if (vo<VO) { atomicAdd(&ssum[vo], sl[s]); atomicAdd(&ssq[vo], ql[s]); }
    }
    __syncthreads();
    const int rep = blockIdx.x & 7;
    for (int i=tid;i<VO;i+=256) {
      atomicAdd(&statN[rep*512+i],        ssum[i]);
      atomicAdd(&statN[4096 + rep*512+i], ssq[i]);
    }
  }
}

extern "C" void kernel_launch(void* const* d_in, const int* in_sizes, int n_in,
                              void* d_out, int out_size, void* d_ws, size_t ws_size,
                              hipStream_t stream)
{
  (void)in_sizes; (void)n_in; (void)out_size; (void)ws_size;
  const float* img = (const float*)d_in[0];
  const float* W0  = (const float*)d_in[1];
  const float* b0  = (const float*)d_in[2];
  const float* g0  = (const float*)d_in[3];
  const float* be0 = (const float*)d_in[4];
  const float* Wr  = (const float*)d_in[5];
  const float* br  = (const float*)d_in[6];
  const float* gr  = (const float*)d_in[7];
  const float* ber = (const float*)d_in[8];

  float* ws = (float*)d_ws;
  // stats: 9 stages x 8192 floats (8 replicas x 512 sum, then 8 x 512 sumsq)
  float* ST = ws;                              // 73728 floats
  unsigned short* Wbt = (unsigned short*)(ws + 73728);   // 1114112 ushorts = 557056 floats
  float* Ca = ws + 73728 + 557056;
  float* Cb = Ca + (size_t)NB*VO;
  float* F  = Cb + (size_t)NB*VO;
  float* out = (float*)d_out;

  zero_stats<<<72,256,0,stream>>>(ST, 9*8192);
  wconv_kernel<<<136,256,0,stream>>>(W0, Wbt);

  conv0_kernel<<<512,256,0,stream>>>(img, Wbt, b0, Ca, ST);

  const int W1 = J*J*J;
  #define STG(j) (ST + (j)*8192)
  // j=0: BN0(g0,be0) -> feat0 (store F), conv Wr[0] -> stats1
  chain_kernel<0,1,1><<<512,256,0,stream>>>(Ca, Cb, F, STG(0), g0,      be0,
                                            Wr+0*W1, br+0*VO, STG(1));
  chain_kernel<0,0,1><<<512,256,0,stream>>>(Cb, Ca, F, STG(1), gr+0*VO, ber+0*VO,
                                            Wr+1*W1, br+1*VO, STG(2));
  chain_kernel<1,1,1><<<512,256,0,stream>>>(Ca, Cb, F, STG(2), gr+1*VO, ber+1*VO,
                                            Wr+2*W1, br+2*VO, STG(3));
  chain_kernel<0,0,1><<<512,256,0,stream>>>(Cb, Ca, F, STG(3), gr+2*VO, ber+2*VO,
                                            Wr+3*W1, br+3*VO, STG(4));
  chain_kernel<1,1,1><<<512,256,0,stream>>>(Ca, Cb, F, STG(4), gr+3*VO, ber+3*VO,
                                            Wr+4*W1, br+4*VO, STG(5));
  chain_kernel<0,0,1><<<512,256,0,stream>>>(Cb, Ca, F, STG(5), gr+4*VO, ber+4*VO,
                                            Wr+5*W1, br+5*VO, STG(6));
  chain_kernel<1,1,1><<<512,256,0,stream>>>(Ca, Cb, F, STG(6), gr+5*VO, ber+5*VO,
                                            Wr+6*W1, br+6*VO, STG(7));
  chain_kernel<0,0,1><<<512,256,0,stream>>>(Cb, Ca, F, STG(7), gr+6*VO, ber+6*VO,
                                            Wr+7*W1, br+7*VO, STG(8));
  // j=8: BN8 -> adj -> relu -> + feat3 -> d_out
  chain_kernel<1,0,0><<<512,256,0,stream>>>(Ca, out, F, STG(8), gr+7*VO, ber+7*VO,
                                            nullptr, nullptr, nullptr);
  #undef STG
}

// Round 7
// 499.530 us; speedup vs baseline: 2.5060x; 1.0072x over previous
//
#include <hip/hip_runtime.h>

#define J 17
#define JP 18             // padded inner dim (2-way LDS bank alias = free)
#define VO 289            // 17*17
#define NB 8192
#define DIN 2048
#define EPSB 1e-5f
#define KC 1024           // conv0: k-floats per staged chunk (4KB per row)
#define RT 16             // conv0: rows per block
#define NCH 34            // 17*2048/1024 chunks per row

typedef __attribute__((ext_vector_type(8))) short bf16x8;
typedef __attribute__((ext_vector_type(4))) float f32x4;

// adjacency (incl. self) as bitmasks, from SKEL
__device__ __constant__ unsigned ADJM[J] = {
  0x7u, 0xFu, 0x17u, 0x2Au, 0x54u, 0x8E8u, 0x1170u, 0x2A0u, 0x540u,
  0x280u, 0x500u, 0x3820u, 0x5840u, 0xA800u, 0x15000u, 0xA000u, 0x14000u};

__device__ inline unsigned short f2bf(float x){
  unsigned u = __float_as_uint(x);
  return (unsigned short)((u + 0x7fffu + ((u>>16)&1u)) >> 16);   // RNE
}

__global__ void zero_stats(float* p, int n) {
  int i = blockIdx.x*blockDim.x + threadIdx.x;
  int stride = gridDim.x*blockDim.x;
  for (; i < n; i += stride) p[i] = 0.f;
}

// -------- prepass: W0 [17][2048][17] f32 -> Wbt [17][32 cols][2048 k] bf16 (cols 17..31 zero)
__global__ __launch_bounds__(256) void wconv_kernel(
    const float* __restrict__ W0, unsigned short* __restrict__ Wbt)
{
  int t = blockIdx.x*256 + threadIdx.x;    // t = v*2048 + k
  int v = t >> 11, k = t & 2047;
  const float* src = W0 + (size_t)t*J;
  unsigned short* dst = Wbt + ((size_t)v*32 << 11) + k;
  #pragma unroll
  for (int o=0;o<J;++o)  dst[(size_t)o<<11] = f2bf(src[o]);
  #pragma unroll
  for (int o=J;o<32;++o) dst[(size_t)o<<11] = 0;
}

// -------- conv0 v3: streaming per-row GEMM, 4KB runs. 512 blocks x 16 rows, block 256 (4 waves).
// chunk c covers floats [c*1024, c*1024+1024) of each row; v = c>>1.
// Loads issued 1 chunk early to regs (16 float4/thread), MFMA on current chunk, write-late.
// Waves k-split the 1024-chunk (256 k each); cross-wave reduce at each v boundary (every 2nd chunk).
__global__ __launch_bounds__(256) void conv0_kernel(
    const float* __restrict__ feat, const unsigned short* __restrict__ Wbt,
    const float* __restrict__ b0, float* __restrict__ C,
    float* __restrict__ stat0)
{
  const int tid = threadIdx.x, w = tid>>6, l = tid&63;
  const int lo = l&15, oc = l>>4;
  const int sr = tid>>4, sc = tid&15;       // staging: row, col-group
  const int rowBase = blockIdx.x*RT;

  __shared__ __align__(16) unsigned short Ab[2][RT*KC];   // 64 KB, XOR-swizzled
  __shared__ float red[4][2][256];                        // 8 KB cross-wave reduce
  __shared__ float bS[VO], bQ[VO];                        // block-local BN stats

  for (int i=tid;i<VO;i+=256){ bS[i]=0.f; bQ[i]=0.f; }

  f32x4 acc0 = (f32x4){0.f,0.f,0.f,0.f};
  f32x4 acc1 = (f32x4){0.f,0.f,0.f,0.f};

  const float* frow = feat + (size_t)(rowBase + sr)*(J*DIN);
  float4 ld[16];

  auto issue = [&](int c){
    const float* src = frow + c*KC + sc*4;
    #pragma unroll
    for (int i=0;i<16;++i) ld[i] = *(const float4*)(src + i*64);
  };
  auto writeLDS = [&](int buf){
    #pragma unroll
    for (int i=0;i<16;++i){
      ushort4 hv;
      hv.x=f2bf(ld[i].x); hv.y=f2bf(ld[i].y); hv.z=f2bf(ld[i].z); hv.w=f2bf(ld[i].w);
      const int f = sc*4 + i*64;
      *(ushort4*)&Ab[buf][(sr*KC + f) ^ ((sr&7)<<3)] = hv;
    }
  };

  issue(0); writeLDS(0);
  __syncthreads();

  const int swz = (lo&7)<<3;

  for (int c=0;c<NCH;++c){
    const int buf = c&1;
    if (c+1<NCH) issue(c+1);
    const int v = c>>1;
    const unsigned short* Wv = Wbt + ((size_t)v*32 << 11);
    #pragma unroll
    for (int ks=0;ks<8;++ks){
      const int kl = w*256 + ks*32 + oc*8;       // k within chunk
      bf16x8 a = *(const bf16x8*)&Ab[buf][(lo*KC + kl) ^ swz];
      const int kg = (c&1)*KC + kl;              // k within v
      bf16x8 bA = *(const bf16x8*)(Wv + ((size_t)lo<<11) + kg);
      bf16x8 bB = *(const bf16x8*)(Wv + ((size_t)(16+lo)<<11) + kg);
      acc0 = __builtin_amdgcn_mfma_f32_16x16x32_bf16(a, bA, acc0, 0,0,0);
      acc1 = __builtin_amdgcn_mfma_f32_16x16x32_bf16(a, bB, acc1, 0,0,0);
    }
    if (c&1){
      // v complete: cross-wave k-split reduce + epilogue
      #pragma unroll
      for (int r=0;r<4;++r){
        red[w][0][(oc*4+r)*16+lo] = acc0[r];
        red[w][1][(oc*4+r)*16+lo] = acc1[r];
      }
      acc0 = (f32x4){0.f,0.f,0.f,0.f};
      acc1 = (f32x4){0.f,0.f,0.f,0.f};
      __syncthreads();
      // thread t = (sr,sc): output row sr, col sc (and col 16 for sc==0)
      const int ri = sr*16+sc;
      float h0 = red[0][0][ri]+red[1][0][ri]+red[2][0][ri]+red[3][0][ri] + b0[v*J+sc];
      C[(size_t)(rowBase+sr)*VO + v*J + sc] = h0;
      float s0 = h0, q0 = h0*h0;
      float s1 = 0.f, q1 = 0.f;
      if (sc==0){
        const int r2 = sr*16;
        float h1 = red[0][1][r2]+red[1][1][r2]+red[2][1][r2]+red[3][1][r2] + b0[v*J+16];
        C[(size_t)(rowBase+sr)*VO + v*J + 16] = h1;
        s1 = h1; q1 = h1*h1;
      }
      s0 += __shfl_xor(s0,16); s0 += __shfl_xor(s0,32);
      q0 += __shfl_xor(q0,16); q0 += __shfl_xor(q0,32);
      s1 += __shfl_xor(s1,16); s1 += __shfl_xor(s1,32);
      q1 += __shfl_xor(q1,16); q1 += __shfl_xor(q1,32);
      if (l < 16){ atomicAdd(&bS[v*J+l], s0); atomicAdd(&bQ[v*J+l], q0); }
      if (l == 0){ atomicAdd(&bS[v*J+16], s1); atomicAdd(&bQ[v*J+16], q1); }
    }
    if (c+1<NCH){
      writeLDS(buf^1);
      __syncthreads();
    }
  }

  __syncthreads();
  const int rep = blockIdx.x & 7;
  for (int i=tid;i<VO;i+=256){
    atomicAdd(&stat0[rep*512+i],        bS[i]);
    atomicAdd(&stat0[4096 + rep*512+i], bQ[i]);
  }
}

// -------- chain: BN_j (8-replica stats) -> bitmask adjacency -> ReLU [-> resid/F]
//          [-> conv_{j+1} (transposed W, 2-row pairing) -> replica stats]
// grid 512 x 16 rows, block 256 (4 waves; each wave 2 pairs of 2 rows)  [round-4 verbatim]
template<int RESID,int WRITEF,int CONV>
__global__ __launch_bounds__(256) void chain_kernel(
  const float* __restrict__ Cin, float* __restrict__ Cout,
  float* __restrict__ F,
  const float* __restrict__ statJ,
  const float* __restrict__ g, const float* __restrict__ be,
  const float* __restrict__ Wc, const float* __restrict__ bc,
  float* __restrict__ statN)
{
  __shared__ float wsmT[J*J*JP];      // [v][o][d], d-contiguous
  __shared__ float bb[VO];
  __shared__ float aC[VO], cC[VO];
  __shared__ float hbX[4][2][J*JP];   // per-wave, 2 rows, [vertex][chan] padded
  __shared__ float ssum[VO], ssq[VO];
  const int tid = threadIdx.x, wv = tid>>6, lane = tid&63;

  if (CONV) {
    for (int i=tid;i<J*J*J;i+=256) {
      int v = i/VO, rem = i - v*VO, d = rem/J, o = rem - d*J;
      wsmT[(v*J+o)*JP + d] = Wc[i];
    }
    for (int i=tid;i<VO;i+=256) bb[i]=bc[i];
  }
  for (int i=tid;i<VO;i+=256) {
    float s=0.f,q=0.f;
    #pragma unroll
    for (int r=0;r<8;++r){ s += statJ[r*512+i]; q += statJ[4096 + r*512+i]; }
    float mu  = s*(1.f/NB);
    float var = q*(1.f/NB) - mu*mu;
    float rs  = rsqrtf(var + EPSB);
    float A = rs*g[i];
    aC[i]=A; cC[i]=be[i]-mu*A;
    ssum[i]=0.f; ssq[i]=0.f;
  }
  __syncthreads();

  float sl[5]={0,0,0,0,0}, ql[5]={0,0,0,0,0};

  #pragma unroll
  for (int it=0; it<2; ++it) {
    const int r0 = blockIdx.x*16 + wv*4 + it*2;   // rows r0, r0+1
    const float* c0 = Cin + (size_t)r0*VO;
    const float* c1 = c0 + VO;

    #pragma unroll
    for (int s=0;s<5;++s) {
      int vo = lane + 64*s;
      if (vo<VO) {
        int vtx = vo/J, o = vo - vtx*J;
        hbX[wv][0][vtx*JP+o] = c0[vo]*aC[vo] + cC[vo];
        hbX[wv][1][vtx*JP+o] = c1[vo]*aC[vo] + cC[vo];
      }
    }
    asm volatile("s_waitcnt lgkmcnt(0)" ::: "memory");

    float n0[5], n1[5];
    #pragma unroll
    for (int s=0;s<5;++s) {
      int vo = lane + 64*s;
      n0[s]=0.f; n1[s]=0.f;
      if (vo<VO) {
        int vtx = vo/J, o = vo - vtx*J;
        unsigned m = ADJM[vtx];
        float a0=0.f, a1=0.f;
        while (m) {
          int u = __ffs(m) - 1; m &= m-1;
          a0 += hbX[wv][0][u*JP+o];
          a1 += hbX[wv][1][u*JP+o];
        }
        a0 = a0>0.f?a0:0.f; a1 = a1>0.f?a1:0.f;
        size_t gi = (size_t)r0*VO + vo;
        if (RESID)  { a0 += F[gi]; a1 += F[gi+VO]; }
        if (WRITEF) { F[gi]=a0;    F[gi+VO]=a1; }
        n0[s]=a0; n1[s]=a1;
        if (!CONV) { Cout[gi]=a0; Cout[gi+VO]=a1; }
      }
    }

    if (CONV) {
      #pragma unroll
      for (int s=0;s<5;++s) {
        int vo = lane + 64*s;
        if (vo<VO) {
          int vtx = vo/J, o = vo - vtx*J;
          hbX[wv][0][vtx*JP+o] = n0[s];
          hbX[wv][1][vtx*JP+o] = n1[s];
        }
      }
      asm volatile("s_waitcnt lgkmcnt(0)" ::: "memory");
      #pragma unroll
      for (int s=0;s<5;++s) {
        int vo = lane + 64*s;
        if (vo<VO) {
          int vtx = vo/J, o = vo - vtx*J;
          const float* wp = &wsmT[(vtx*J+o)*JP];
          const float* h0 = &hbX[wv][0][vtx*JP];
          const float* h1 = &hbX[wv][1][vtx*JP];
          float a0 = bb[vo], a1 = a0;
          #pragma unroll
          for (int d=0;d<J;++d) {
            float w = wp[d];
            a0 += h0[d]*w; a1 += h1[d]*w;
          }
          size_t gi = (size_t)r0*VO + vo;
          Cout[gi]=a0; Cout[gi+VO]=a1;
          sl[s] += a0+a1; ql[s] += a0*a0 + a1*a1;
        }
      }
      asm volatile("s_waitcnt lgkmcnt(0)" ::: "memory");
    } else {
      asm volatile("s_waitcnt lgkmcnt(0)" ::: "memory");
    }
  }

  if (CONV) {
    #pragma unroll
    for (int s=0;s<5;++s) {
      int vo = lane + 64*s;
      if (vo<VO) { atomicAdd(&ssum[vo], sl[s]); atomicAdd(&ssq[vo], ql[s]); }
    }
    __syncthreads();
    const int rep = blockIdx.x & 7;
    for (int i=tid;i<VO;i+=256) {
      atomicAdd(&statN[rep*512+i],        ssum[i]);
      atomicAdd(&statN[4096 + rep*512+i], ssq[i]);
    }
  }
}

extern "C" void kernel_launch(void* const* d_in, const int* in_sizes, int n_in,
                              void* d_out, int out_size, void* d_ws, size_t ws_size,
                              hipStream_t stream)
{
  (void)in_sizes; (void)n_in; (void)out_size; (void)ws_size;
  const float* img = (const float*)d_in[0];
  const float* W0  = (const float*)d_in[1];
  const float* b0  = (const float*)d_in[2];
  const float* g0  = (const float*)d_in[3];
  const float* be0 = (const float*)d_in[4];
  const float* Wr  = (const float*)d_in[5];
  const float* br  = (const float*)d_in[6];
  const float* gr  = (const float*)d_in[7];
  const float* ber = (const float*)d_in[8];

  float* ws = (float*)d_ws;
  // stats: 9 stages x 8192 floats (8 replicas x 512 sum, then 8 x 512 sumsq)
  float* ST = ws;                              // 73728 floats
  unsigned short* Wbt = (unsigned short*)(ws + 73728);   // 1114112 ushorts = 557056 floats
  float* Ca = ws + 73728 + 557056;
  float* Cb = Ca + (size_t)NB*VO;
  float* F  = Cb + (size_t)NB*VO;
  float* out = (float*)d_out;

  zero_stats<<<72,256,0,stream>>>(ST, 9*8192);
  wconv_kernel<<<136,256,0,stream>>>(W0, Wbt);

  conv0_kernel<<<512,256,0,stream>>>(img, Wbt, b0, Ca, ST);

  const int W1 = J*J*J;
  #define STG(j) (ST + (j)*8192)
  // j=0: BN0(g0,be0) -> feat0 (store F), conv Wr[0] -> stats1
  chain_kernel<0,1,1><<<512,256,0,stream>>>(Ca, Cb, F, STG(0), g0,      be0,
                                            Wr+0*W1, br+0*VO, STG(1));
  chain_kernel<0,0,1><<<512,256,0,stream>>>(Cb, Ca, F, STG(1), gr+0*VO, ber+0*VO,
                                            Wr+1*W1, br+1*VO, STG(2));
  chain_kernel<1,1,1><<<512,256,0,stream>>>(Ca, Cb, F, STG(2), gr+1*VO, ber+1*VO,
                                            Wr+2*W1, br+2*VO, STG(3));
  chain_kernel<0,0,1><<<512,256,0,stream>>>(Cb, Ca, F, STG(3), gr+2*VO, ber+2*VO,
                                            Wr+3*W1, br+3*VO, STG(4));
  chain_kernel<1,1,1><<<512,256,0,stream>>>(Ca, Cb, F, STG(4), gr+3*VO, ber+3*VO,
                                            Wr+4*W1, br+4*VO, STG(5));
  chain_kernel<0,0,1><<<512,256,0,stream>>>(Cb, Ca, F, STG(5), gr+4*VO, ber+4*VO,
                                            Wr+5*W1, br+5*VO, STG(6));
  chain_kernel<1,1,1><<<512,256,0,stream>>>(Ca, Cb, F, STG(6), gr+5*VO, ber+5*VO,
                                            Wr+6*W1, br+6*VO, STG(7));
  chain_kernel<0,0,1><<<512,256,0,stream>>>(Cb, Ca, F, STG(7), gr+6*VO, ber+6*VO,
                                            Wr+7*W1, br+7*VO, STG(8));
  // j=8: BN8 -> adj -> relu -> + feat3 -> d_out
  chain_kernel<1,0,0><<<512,256,0,stream>>>(Ca, out, F, STG(8), gr+7*VO, ber+7*VO,
                                            nullptr, nullptr, nullptr);
  #undef STG
}

// Round 8
// 499.405 us; speedup vs baseline: 2.5066x; 1.0003x over previous
//
#include <hip/hip_runtime.h>

#define J 17
#define JP 18             // padded inner dim (2-way LDS bank alias = free)
#define VO 289            // 17*17
#define NB 8192
#define DIN 2048
#define EPSB 1e-5f
#define KC 1024           // conv0: k-floats per staged chunk (4KB per row)
#define RT 16             // conv0: rows per block
#define NCH 34            // 17*2048/1024 chunks per row

typedef __attribute__((ext_vector_type(8))) short bf16x8;
typedef __attribute__((ext_vector_type(4))) float f32x4;

// adjacency (incl. self) as bitmasks, from SKEL
__device__ __constant__ unsigned ADJM[J] = {
  0x7u, 0xFu, 0x17u, 0x2Au, 0x54u, 0x8E8u, 0x1170u, 0x2A0u, 0x540u,
  0x280u, 0x500u, 0x3820u, 0x5840u, 0xA800u, 0x15000u, 0xA000u, 0x14000u};

__device__ inline unsigned short f2bf(float x){
  unsigned u = __float_as_uint(x);
  return (unsigned short)((u + 0x7fffu + ((u>>16)&1u)) >> 16);   // RNE
}

__global__ void zero_stats(float* p, int n) {
  int i = blockIdx.x*blockDim.x + threadIdx.x;
  int stride = gridDim.x*blockDim.x;
  for (; i < n; i += stride) p[i] = 0.f;
}

// -------- prepass: W0 [17][2048][17] f32 -> Wbt [17][32 cols][2048 k] bf16 (cols 17..31 zero)
__global__ __launch_bounds__(256) void wconv_kernel(
    const float* __restrict__ W0, unsigned short* __restrict__ Wbt)
{
  int t = blockIdx.x*256 + threadIdx.x;    // t = v*2048 + k
  int v = t >> 11, k = t & 2047;
  const float* src = W0 + (size_t)t*J;
  unsigned short* dst = Wbt + ((size_t)v*32 << 11) + k;
  #pragma unroll
  for (int o=0;o<J;++o)  dst[(size_t)o<<11] = f2bf(src[o]);
  #pragma unroll
  for (int o=J;o<32;++o) dst[(size_t)o<<11] = 0;
}

// -------- conv0 v3: streaming per-row GEMM, 4KB runs. 512 blocks x 16 rows, block 256 (4 waves).
// chunk c covers floats [c*1024, c*1024+1024) of each row; v = c>>1.
// Loads issued 1 chunk early to regs (16 float4/thread), MFMA on current chunk, write-late.
// Waves k-split the 1024-chunk (256 k each); cross-wave reduce at each v boundary (every 2nd chunk).
__global__ __launch_bounds__(256) void conv0_kernel(
    const float* __restrict__ feat, const unsigned short* __restrict__ Wbt,
    const float* __restrict__ b0, float* __restrict__ C,
    float* __restrict__ stat0)
{
  const int tid = threadIdx.x, w = tid>>6, l = tid&63;
  const int lo = l&15, oc = l>>4;
  const int sr = tid>>4, sc = tid&15;       // staging: row, col-group
  const int rowBase = blockIdx.x*RT;

  __shared__ __align__(16) unsigned short Ab[2][RT*KC];   // 64 KB, XOR-swizzled
  __shared__ float red[4][2][256];                        // 8 KB cross-wave reduce
  __shared__ float bS[VO], bQ[VO];                        // block-local BN stats

  for (int i=tid;i<VO;i+=256){ bS[i]=0.f; bQ[i]=0.f; }

  f32x4 acc0 = (f32x4){0.f,0.f,0.f,0.f};
  f32x4 acc1 = (f32x4){0.f,0.f,0.f,0.f};

  const float* frow = feat + (size_t)(rowBase + sr)*(J*DIN);
  float4 ld[16];

  auto issue = [&](int c){
    const float* src = frow + c*KC + sc*4;
    #pragma unroll
    for (int i=0;i<16;++i) ld[i] = *(const float4*)(src + i*64);
  };
  auto writeLDS = [&](int buf){
    #pragma unroll
    for (int i=0;i<16;++i){
      ushort4 hv;
      hv.x=f2bf(ld[i].x); hv.y=f2bf(ld[i].y); hv.z=f2bf(ld[i].z); hv.w=f2bf(ld[i].w);
      const int f = sc*4 + i*64;
      *(ushort4*)&Ab[buf][(sr*KC + f) ^ ((sr&7)<<3)] = hv;
    }
  };

  issue(0); writeLDS(0);
  __syncthreads();

  const int swz = (lo&7)<<3;

  for (int c=0;c<NCH;++c){
    const int buf = c&1;
    if (c+1<NCH) issue(c+1);
    const int v = c>>1;
    const unsigned short* Wv = Wbt + ((size_t)v*32 << 11);
    #pragma unroll
    for (int ks=0;ks<8;++ks){
      const int kl = w*256 + ks*32 + oc*8;       // k within chunk
      bf16x8 a = *(const bf16x8*)&Ab[buf][(lo*KC + kl) ^ swz];
      const int kg = (c&1)*KC + kl;              // k within v
      bf16x8 bA = *(const bf16x8*)(Wv + ((size_t)lo<<11) + kg);
      bf16x8 bB = *(const bf16x8*)(Wv + ((size_t)(16+lo)<<11) + kg);
      acc0 = __builtin_amdgcn_mfma_f32_16x16x32_bf16(a, bA, acc0, 0,0,0);
      acc1 = __builtin_amdgcn_mfma_f32_16x16x32_bf16(a, bB, acc1, 0,0,0);
    }
    if (c&1){
      // v complete: cross-wave k-split reduce + epilogue
      #pragma unroll
      for (int r=0;r<4;++r){
        red[w][0][(oc*4+r)*16+lo] = acc0[r];
        red[w][1][(oc*4+r)*16+lo] = acc1[r];
      }
      acc0 = (f32x4){0.f,0.f,0.f,0.f};
      acc1 = (f32x4){0.f,0.f,0.f,0.f};
      __syncthreads();
      // thread t = (sr,sc): output row sr, col sc (and col 16 for sc==0)
      const int ri = sr*16+sc;
      float h0 = red[0][0][ri]+red[1][0][ri]+red[2][0][ri]+red[3][0][ri] + b0[v*J+sc];
      C[(size_t)(rowBase+sr)*VO + v*J + sc] = h0;
      float s0 = h0, q0 = h0*h0;
      float s1 = 0.f, q1 = 0.f;
      if (sc==0){
        const int r2 = sr*16;
        float h1 = red[0][1][r2]+red[1][1][r2]+red[2][1][r2]+red[3][1][r2] + b0[v*J+16];
        C[(size_t)(rowBase+sr)*VO + v*J + 16] = h1;
        s1 = h1; q1 = h1*h1;
      }
      s0 += __shfl_xor(s0,16); s0 += __shfl_xor(s0,32);
      q0 += __shfl_xor(q0,16); q0 += __shfl_xor(q0,32);
      s1 += __shfl_xor(s1,16); s1 += __shfl_xor(s1,32);
      q1 += __shfl_xor(q1,16); q1 += __shfl_xor(q1,32);
      if (l < 16){ atomicAdd(&bS[v*J+l], s0); atomicAdd(&bQ[v*J+l], q0); }
      if (l == 0){ atomicAdd(&bS[v*J+16], s1); atomicAdd(&bQ[v*J+16], q1); }
    }
    if (c+1<NCH){
      writeLDS(buf^1);
      __syncthreads();
    }
  }

  __syncthreads();
  const int rep = blockIdx.x & 7;
  for (int i=tid;i<VO;i+=256){
    atomicAdd(&stat0[rep*512+i],        bS[i]);
    atomicAdd(&stat0[4096 + rep*512+i], bQ[i]);
  }
}

// -------- chain: BN_j (8-replica stats) -> bitmask adjacency -> ReLU [-> resid/F]
//          [-> conv_{j+1} (transposed W, 2-row pairing) -> replica stats]
// grid 512 x 16 rows, block 256 (4 waves; each wave 2 pairs of 2 rows)  [round-4 verbatim]
template<int RESID,int WRITEF,int CONV>
__global__ __launch_bounds__(256) void chain_kernel(
  const float* __restrict__ Cin, float* __restrict__ Cout,
  float* __restrict__ F,
  const float* __restrict__ statJ,
  const float* __restrict__ g, const float* __restrict__ be,
  const float* __restrict__ Wc, const float* __restrict__ bc,
  float* __restrict__ statN)
{
  __shared__ float wsmT[J*J*JP];      // [v][o][d], d-contiguous
  __shared__ float bb[VO];
  __shared__ float aC[VO], cC[VO];
  __shared__ float hbX[4][2][J*JP];   // per-wave, 2 rows, [vertex][chan] padded
  __shared__ float ssum[VO], ssq[VO];
  const int tid = threadIdx.x, wv = tid>>6, lane = tid&63;

  if (CONV) {
    for (int i=tid;i<J*J*J;i+=256) {
      int v = i/VO, rem = i - v*VO, d = rem/J, o = rem - d*J;
      wsmT[(v*J+o)*JP + d] = Wc[i];
    }
    for (int i=tid;i<VO;i+=256) bb[i]=bc[i];
  }
  for (int i=tid;i<VO;i+=256) {
    float s=0.f,q=0.f;
    #pragma unroll
    for (int r=0;r<8;++r){ s += statJ[r*512+i]; q += statJ[4096 + r*512+i]; }
    float mu  = s*(1.f/NB);
    float var = q*(1.f/NB) - mu*mu;
    float rs  = rsqrtf(var + EPSB);
    float A = rs*g[i];
    aC[i]=A; cC[i]=be[i]-mu*A;
    ssum[i]=0.f; ssq[i]=0.f;
  }
  __syncthreads();

  float sl[5]={0,0,0,0,0}, ql[5]={0,0,0,0,0};

  #pragma unroll
  for (int it=0; it<2; ++it) {
    const int r0 = blockIdx.x*16 + wv*4 + it*2;   // rows r0, r0+1
    const float* c0 = Cin + (size_t)r0*VO;
    const float* c1 = c0 + VO;

    #pragma unroll
    for (int s=0;s<5;++s) {
      int vo = lane + 64*s;
      if (vo<VO) {
        int vtx = vo/J, o = vo - vtx*J;
        hbX[wv][0][vtx*JP+o] = c0[vo]*aC[vo] + cC[vo];
        hbX[wv][1][vtx*JP+o] = c1[vo]*aC[vo] + cC[vo];
      }
    }
    asm volatile("s_waitcnt lgkmcnt(0)" ::: "memory");

    float n0[5], n1[5];
    #pragma unroll
    for (int s=0;s<5;++s) {
      int vo = lane + 64*s;
      n0[s]=0.f; n1[s]=0.f;
      if (vo<VO) {
        int vtx = vo/J, o = vo - vtx*J;
        unsigned m = ADJM[vtx];
        float a0=0.f, a1=0.f;
        while (m) {
          int u = __ffs(m) - 1; m &= m-1;
          a0 += hbX[wv][0][u*JP+o];
          a1 += hbX[wv][1][u*JP+o];
        }
        a0 = a0>0.f?a0:0.f; a1 = a1>0.f?a1:0.f;
        size_t gi = (size_t)r0*VO + vo;
        if (RESID)  { a0 += F[gi]; a1 += F[gi+VO]; }
        if (WRITEF) { F[gi]=a0;    F[gi+VO]=a1; }
        n0[s]=a0; n1[s]=a1;
        if (!CONV) { Cout[gi]=a0; Cout[gi+VO]=a1; }
      }
    }

    if (CONV) {
      #pragma unroll
      for (int s=0;s<5;++s) {
        int vo = lane + 64*s;
        if (vo<VO) {
          int vtx = vo/J, o = vo - vtx*J;
          hbX[wv][0][vtx*JP+o] = n0[s];
          hbX[wv][1][vtx*JP+o] = n1[s];
        }
      }
      asm volatile("s_waitcnt lgkmcnt(0)" ::: "memory");
      #pragma unroll
      for (int s=0;s<5;++s) {
        int vo = lane + 64*s;
        if (vo<VO) {
          int vtx = vo/J, o = vo - vtx*J;
          const float* wp = &wsmT[(vtx*J+o)*JP];
          const float* h0 = &hbX[wv][0][vtx*JP];
          const float* h1 = &hbX[wv][1][vtx*JP];
          float a0 = bb[vo], a1 = a0;
          #pragma unroll
          for (int d=0;d<J;++d) {
            float w = wp[d];
            a0 += h0[d]*w; a1 += h1[d]*w;
          }
          size_t gi = (size_t)r0*VO + vo;
          Cout[gi]=a0; Cout[gi+VO]=a1;
          sl[s] += a0+a1; ql[s] += a0*a0 + a1*a1;
        }
      }
      asm volatile("s_waitcnt lgkmcnt(0)" ::: "memory");
    } else {
      asm volatile("s_waitcnt lgkmcnt(0)" ::: "memory");
    }
  }

  if (CONV) {
    #pragma unroll
    for (int s=0;s<5;++s) {
      int vo = lane + 64*s;
      if (vo<VO) { atomicAdd(&ssum[vo], sl[s]); atomicAdd(&ssq[vo], ql[s]); }
    }
    __syncthreads();
    const int rep = blockIdx.x & 7;
    for (int i=tid;i<VO;i+=256) {
      atomicAdd(&statN[rep*512+i],        ssum[i]);
      atomicAdd(&statN[4096 + rep*512+i], ssq[i]);
    }
  }
}

extern "C" void kernel_launch(void* const* d_in, const int* in_sizes, int n_in,
                              void* d_out, int out_size, void* d_ws, size_t ws_size,
                              hipStream_t stream)
{
  (void)in_sizes; (void)n_in; (void)out_size; (void)ws_size;
  const float* img = (const float*)d_in[0];
  const float* W0  = (const float*)d_in[1];
  const float* b0  = (const float*)d_in[2];
  const float* g0  = (const float*)d_in[3];
  const float* be0 = (const float*)d_in[4];
  const float* Wr  = (const float*)d_in[5];
  const float* br  = (const float*)d_in[6];
  const float* gr  = (const float*)d_in[7];
  const float* ber = (const float*)d_in[8];

  float* ws = (float*)d_ws;
  // stats: 9 stages x 8192 floats (8 replicas x 512 sum, then 8 x 512 sumsq)
  float* ST = ws;                              // 73728 floats
  unsigned short* Wbt = (unsigned short*)(ws + 73728);   // 1114112 ushorts = 557056 floats
  float* Ca = ws + 73728 + 557056;
  float* Cb = Ca + (size_t)NB*VO;
  float* F  = Cb + (size_t)NB*VO;
  float* out = (float*)d_out;

  zero_stats<<<72,256,0,stream>>>(ST, 9*8192);
  wconv_kernel<<<136,256,0,stream>>>(W0, Wbt);

  conv0_kernel<<<512,256,0,stream>>>(img, Wbt, b0, Ca, ST);

  const int W1 = J*J*J;
  #define STG(j) (ST + (j)*8192)
  // j=0: BN0(g0,be0) -> feat0 (store F), conv Wr[0] -> stats1
  chain_kernel<0,1,1><<<512,256,0,stream>>>(Ca, Cb, F, STG(0), g0,      be0,
                                            Wr+0*W1, br+0*VO, STG(1));
  chain_kernel<0,0,1><<<512,256,0,stream>>>(Cb, Ca, F, STG(1), gr+0*VO, ber+0*VO,
                                            Wr+1*W1, br+1*VO, STG(2));
  chain_kernel<1,1,1><<<512,256,0,stream>>>(Ca, Cb, F, STG(2), gr+1*VO, ber+1*VO,
                                            Wr+2*W1, br+2*VO, STG(3));
  chain_kernel<0,0,1><<<512,256,0,stream>>>(Cb, Ca, F, STG(3), gr+2*VO, ber+2*VO,
                                            Wr+3*W1, br+3*VO, STG(4));
  chain_kernel<1,1,1><<<512,256,0,stream>>>(Ca, Cb, F, STG(4), gr+3*VO, ber+3*VO,
                                            Wr+4*W1, br+4*VO, STG(5));
  chain_kernel<0,0,1><<<512,256,0,stream>>>(Cb, Ca, F, STG(5), gr+4*VO, ber+4*VO,
                                            Wr+5*W1, br+5*VO, STG(6));
  chain_kernel<1,1,1><<<512,256,0,stream>>>(Ca, Cb, F, STG(6), gr+5*VO, ber+5*VO,
                                            Wr+6*W1, br+6*VO, STG(7));
  chain_kernel<0,0,1><<<512,256,0,stream>>>(Cb, Ca, F, STG(7), gr+6*VO, ber+6*VO,
                                            Wr+7*W1, br+7*VO, STG(8));
  // j=8: BN8 -> adj -> relu -> + feat3 -> d_out
  chain_kernel<1,0,0><<<512,256,0,stream>>>(Ca, out, F, STG(8), gr+7*VO, ber+7*VO,
                                            nullptr, nullptr, nullptr);
  #undef STG
}